// Round 6
// baseline (195.721 us; speedup 1.0000x reference)
//
#include <hip/hip_runtime.h>

// EfficientAttention (linear attention / Performer-style), MI355X gfx950.
// B=4, S=8192, H=512, NH=8, HD=64, FD=32. All inputs fp32; output fp32.
//
// R6: cvt_x fused into gemm_qkv (A-path reg-staged fp32->bf16 via
// v_cvt_pk_bf16_f32 + ds_write, hidden under MFMA; __syncthreads-only sync),
// kv_partial split 32->64 S-chunks (2x wave occupancy), mprep+qn merged.
// Proven R5 K-loop structure and epilogues unchanged; no counted vmcnt.
//
//  K0  prep_w  : WcatT[n][k] bf16 (n<256:(Wq@rm)^T, n<512:(Wk@rm)^T, else Wv^T)
//  K1  gemm_qkv: x(fp32) @ WcatT^T; elu+1 on feature cols; QF token-major,
//                KFT/VT transposed (bh,d|f,s) via per-wave LDS transpose.
//  K2  kv_part : per (b,h): kv[d][f] = sum_s k'[s][d] v[s][f]; ksum folded.
//  K2b kv_red  : partials -> kvr[bh][2080] (2048 kv + 32 ksum) fp32
//  K3  mprep_qn: blocks<2048: MT[b][n][k]=sum_f kv*Wout (bf16);
//                blocks>=2048: qn = q'/(q'.ksum+1e-6) (bf16)
//  K4  gemm_out: out[b] = qn[b] @ M[b]^T + b_out  (K=256, B-panel LDS-resident)

#define DEVFN static __device__ __forceinline__

typedef short short8 __attribute__((ext_vector_type(8)));
typedef __bf16 bf16x8 __attribute__((ext_vector_type(8)));
typedef float f32x4 __attribute__((ext_vector_type(4)));
typedef unsigned uint32x4 __attribute__((ext_vector_type(4)));

DEVFN unsigned short f2bf(float x) {
  unsigned u = __float_as_uint(x);
  u += 0x7FFFu + ((u >> 16) & 1u);   // RNE
  return (unsigned short)(u >> 16);
}
DEVFN float bf2f(unsigned short s) { return __uint_as_float(((unsigned)s) << 16); }

DEVFN unsigned cvtpk(float lo, float hi) {   // packs 2 f32 -> 2 bf16 (RNE)
  unsigned r;
  asm("v_cvt_pk_bf16_f32 %0, %1, %2" : "=v"(r) : "v"(lo), "v"(hi));
  return r;
}

DEVFN f32x4 mfma16(short8 a, short8 b, f32x4 c) {
  return __builtin_amdgcn_mfma_f32_16x16x32_bf16(
      __builtin_bit_cast(bf16x8, a), __builtin_bit_cast(bf16x8, b), c, 0, 0, 0);
}

DEVFN void gload16(const void* g, void* l) {
  __builtin_amdgcn_global_load_lds((__attribute__((address_space(1))) unsigned*)g,
                                   (__attribute__((address_space(3))) unsigned*)l,
                                   16, 0, 0);
}

// ---------------- K0: weight prep ----------------
__global__ __launch_bounds__(64) void prep_w(const float* __restrict__ Wqkv,
                                             const float* __restrict__ rm,
                                             unsigned short* __restrict__ WcatT) {
  const int n = blockIdx.x, t = threadIdx.x;
  if (n < 512) {
    const int isK = (n >= 256) ? 1 : 0;
    const int c = n & 255, h = c >> 5, d = c & 31;
    const int colbase = isK * 512 + h * 64;
    for (int k = t; k < 512; k += 64) {
      float s = 0.f;
      const float* wrow = Wqkv + (size_t)k * 1536 + colbase;
      #pragma unroll 8
      for (int e = 0; e < 64; ++e) s += wrow[e] * rm[e * 32 + d];
      WcatT[(size_t)n * 512 + k] = f2bf(s);
    }
  } else {
    const int c = n - 512;
    for (int k = t; k < 512; k += 64)
      WcatT[(size_t)n * 512 + k] = f2bf(Wqkv[(size_t)k * 1536 + 1024 + c]);
  }
}

// ---------------- K1: qkv GEMM, K=512, fused fp32->bf16 A-staging ----------
__global__ __launch_bounds__(256) void gemm_qkv(
    const float* __restrict__ X,            // 32768 x 512 fp32
    const unsigned short* __restrict__ BT,  // 1024 x 512 bf16
    unsigned short* __restrict__ OQ,
    unsigned short* __restrict__ OK,
    unsigned short* __restrict__ OV) {
  // K-loop: A bufs [0,8192), B bufs [8192,16384) shorts (32 KB).
  // Epilogue transpose (after last __syncthreads): 4 x 4352 = 17408 shorts.
  __shared__ __attribute__((aligned(16))) unsigned short lds[18432];  // 36 KB
  const int t = threadIdx.x;
  const int lane = t & 63, w = t >> 6;
  const int wr = w >> 1, wc = w & 1;
  const int col = lane & 15, kg = lane >> 4;

  // XCD-chunked swizzle (2048 wgs, %8==0)
  const int nx = gridDim.x;
  int wg = blockIdx.y * nx + blockIdx.x;
  const int cpx = (nx * (int)gridDim.y) >> 3;
  wg = (wg & 7) * cpx + (wg >> 3);
  const int bx = wg % nx, by = wg / nx;

  const long m0 = (long)by * 128;
  const long n0 = (long)bx * 128;

  const float* gx = X + (m0 + (t >> 2)) * 512 + (t & 3) * 8;
  const unsigned short* gb = BT + (n0 + (t >> 2)) * 512 + (t & 3) * 8;

  f32x4 acc[4][4] = {};
  f32x4 ra0, ra1, ra2, ra3;   // in-flight fp32 A-chunk (rows r and r+64)

#define LOADA(kt)                               \
  {                                             \
    const int ko_ = (kt) * 32;                  \
    ra0 = *(const f32x4*)(gx + ko_);            \
    ra1 = *(const f32x4*)(gx + ko_ + 4);        \
    ra2 = *(const f32x4*)(gx + 32768 + ko_);    \
    ra3 = *(const f32x4*)(gx + 32768 + ko_ + 4);\
  }
#define CVTWRITE(buf)                                         \
  {                                                           \
    unsigned short* la_ = lds + (buf) * 4096 + t * 8;         \
    uint32x4 o0, o1;                                          \
    o0[0] = cvtpk(ra0[0], ra0[1]); o0[1] = cvtpk(ra0[2], ra0[3]); \
    o0[2] = cvtpk(ra1[0], ra1[1]); o0[3] = cvtpk(ra1[2], ra1[3]); \
    o1[0] = cvtpk(ra2[0], ra2[1]); o1[1] = cvtpk(ra2[2], ra2[3]); \
    o1[2] = cvtpk(ra3[0], ra3[1]); o1[3] = cvtpk(ra3[2], ra3[3]); \
    *(uint32x4*)la_ = o0;                                     \
    *(uint32x4*)(la_ + 2048) = o1;                            \
  }
#define STAGEB(buf, kt)                                       \
  {                                                           \
    const int ko_ = (kt) * 32;                                \
    unsigned short* lb_ = lds + 8192 + (buf) * 4096 + w * 512;\
    gload16(gb + ko_, lb_);                                   \
    gload16(gb + 32768 + ko_, lb_ + 2048);                    \
  }

  LOADA(0)
  CVTWRITE(0)
  STAGEB(0, 0)
  __syncthreads();                 // drains vmcnt(0)+lgkmcnt(0): tile 0 resident
  int buf = 0;
  for (int kt = 0; kt < 16; ++kt) {
    if (kt + 1 < 16) {
      LOADA(kt + 1)                // issue fp32 loads early (hide under MFMA)
      STAGEB(buf ^ 1, kt + 1)      // B DMA for next tile
    }
    const unsigned short* As_ = lds + buf * 4096;
    const unsigned short* Bs_ = lds + 8192 + buf * 4096;
    short8 af[4], bfr[4];
    #pragma unroll
    for (int mi = 0; mi < 4; ++mi)
      af[mi] = *(const short8*)&As_[(wr * 64 + mi * 16 + col) * 32 + kg * 8];
    #pragma unroll
    for (int ni = 0; ni < 4; ++ni)
      bfr[ni] = *(const short8*)&Bs_[(wc * 64 + ni * 16 + col) * 32 + kg * 8];
    #pragma unroll
    for (int mi = 0; mi < 4; ++mi)
      #pragma unroll
      for (int ni = 0; ni < 4; ++ni)
        acc[mi][ni] = mfma16(af[mi], bfr[ni], acc[mi][ni]);
    if (kt + 1 < 16) CVTWRITE(buf ^ 1)   // cvt arrived loads, write next A buf
    __syncthreads();               // drains B DMA + own ds_writes; publishes buf^1
    buf ^= 1;
  }
#undef LOADA
#undef CVTWRITE
#undef STAGEB

  const int rowb = (int)m0 + wr * 64;
  const int colb = (int)n0 + wc * 64;
  const int b_ = rowb >> 13, srow = rowb & 8191;

  if (colb < 256) {
    // Q quadrant: token-major direct stores, elu+1
    #pragma unroll
    for (int ni = 0; ni < 4; ++ni) {
      const int c = colb + ni * 16 + col;
      #pragma unroll
      for (int mi = 0; mi < 4; ++mi) {
        #pragma unroll
        for (int r = 0; r < 4; ++r) {
          const int row = rowb + mi * 16 + kg * 4 + r;
          float v = acc[mi][ni][r];
          v = v > 0.f ? v + 1.f : __expf(v);
          OQ[(size_t)row * 256 + c] = f2bf(v);
        }
      }
    }
  } else {
    // K/V quadrant: per-wave 64x64 LDS transpose, then coalesced 16B stores.
    const bool isK = (colb < 512);
    unsigned short* q_ = lds + w * 4352;   // 64 x 64, row stride 68 elements
    #pragma unroll
    for (int ni = 0; ni < 4; ++ni) {
      const int p = ni * 16 + col;
      #pragma unroll
      for (int mi = 0; mi < 4; ++mi) {
        #pragma unroll
        for (int r = 0; r < 4; ++r) {
          const int q = mi * 16 + kg * 4 + r;
          float v = acc[mi][ni][r];
          if (isK) v = v > 0.f ? v + 1.f : __expf(v);
          q_[q * 68 + p] = f2bf(v);
        }
      }
    }
    asm volatile("s_waitcnt lgkmcnt(0)" ::: "memory");  // own-wave writes done
    __builtin_amdgcn_sched_barrier(0);
    const int pg = lane >> 3, jj = lane & 7;
    #pragma unroll
    for (int it = 0; it < 8; ++it) {
      const int p = pg + it * 8;          // column of quadrant
      const int c = colb + p;
      size_t rowf;
      if (isK) rowf = (size_t)(b_ * 8 + ((c - 256) >> 5)) * 32 + ((c - 256) & 31);
      else     rowf = (size_t)(b_ * 8 + ((c - 512) >> 6)) * 64 + ((c - 512) & 63);
      unsigned short* dst = (isK ? OK : OV) + rowf * 8192 + srow + jj * 8;
      short8 o;
      #pragma unroll
      for (int i = 0; i < 8; ++i)
        o[i] = (short)q_[(jj * 8 + i) * 68 + p];
      *(short8*)dst = o;
    }
  }
}

// ---------------- K2: kv partials per (b,h), 64 S-chunks ----------------
__global__ __launch_bounds__(64) void kv_partial(const unsigned short* __restrict__ KFT,
                                                 const unsigned short* __restrict__ VT,
                                                 float* __restrict__ part) {
  const int bh = blockIdx.x, chunk = blockIdx.y;
  const int l = threadIdx.x;
  const int col = l & 15, kg = l >> 4;
  const unsigned short* Ab = KFT + (size_t)bh * 32 * 8192;
  const unsigned short* Bb = VT + (size_t)bh * 64 * 8192;
  const int s0 = chunk * 128;
  f32x4 acc[2][4] = {};
  float ksp[2] = {0.f, 0.f};
  #pragma unroll
  for (int st = 0; st < 4; ++st) {
    const int s = s0 + st * 32 + kg * 8;
    short8 a[2], b[4];
    #pragma unroll
    for (int mi = 0; mi < 2; ++mi)
      a[mi] = *(const short8*)&Ab[(size_t)(mi * 16 + col) * 8192 + s];
    #pragma unroll
    for (int ni = 0; ni < 4; ++ni)
      b[ni] = *(const short8*)&Bb[(size_t)(ni * 16 + col) * 8192 + s];
    #pragma unroll
    for (int mi = 0; mi < 2; ++mi) {
      #pragma unroll
      for (int j = 0; j < 8; ++j) ksp[mi] += bf2f((unsigned short)a[mi][j]);
      #pragma unroll
      for (int ni = 0; ni < 4; ++ni)
        acc[mi][ni] = mfma16(a[mi], b[ni], acc[mi][ni]);
    }
  }
  #pragma unroll
  for (int mi = 0; mi < 2; ++mi) {
    float v = ksp[mi];
    v += __shfl_xor(v, 16);
    v += __shfl_xor(v, 32);
    ksp[mi] = v;
  }
  float* p = part + ((size_t)bh * 64 + chunk) * 2080;
  #pragma unroll
  for (int mi = 0; mi < 2; ++mi)
    #pragma unroll
    for (int ni = 0; ni < 4; ++ni)
      #pragma unroll
      for (int r = 0; r < 4; ++r) {
        const int d = mi * 16 + kg * 4 + r, f = ni * 16 + col;
        p[d * 64 + f] = acc[mi][ni][r];
      }
  if (kg == 0) {
    p[2048 + col] = ksp[0];
    p[2048 + 16 + col] = ksp[1];
  }
}

// ---------------- K2b: reduce partials ----------------
__global__ __launch_bounds__(256) void kv_reduce(const float* __restrict__ part,
                                                 float* __restrict__ kvr) {
  const int bh = blockIdx.x, t = threadIdx.x;
  for (int idx = t; idx < 2080; idx += 256) {
    float s = 0.f;
    for (int c = 0; c < 64; ++c) s += part[((size_t)bh * 64 + c) * 2080 + idx];
    kvr[(size_t)bh * 2080 + idx] = s;
  }
}

// ---------------- K3: merged mprep (blocks<2048) + qn (blocks>=2048) --------
__global__ __launch_bounds__(256) void mprep_qn(const float* __restrict__ kvr,
                                                const float* __restrict__ Wout,
                                                const unsigned short* __restrict__ QF,
                                                unsigned short* __restrict__ MT,
                                                unsigned short* __restrict__ QN) {
  __shared__ float ks[256];
  const int t = threadIdx.x;
  if (blockIdx.x < 2048) {
    // MT[b][n][k=h*32+d] = sum_f kv[b,h,d,f] * Wout[h*64+f][n]
    const int bx = blockIdx.x;
    const int b = bx >> 9, n = bx & 511;
    const int h = t >> 5, d = t & 31;
    const float* kvp = kvr + (size_t)(b * 8 + h) * 2080 + d * 64;
    const float* wp = Wout + (size_t)h * 64 * 512 + n;
    float s = 0.f;
    #pragma unroll 8
    for (int f = 0; f < 64; ++f) s += kvp[f] * wp[(size_t)f * 512];
    MT[((size_t)b * 512 + n) * 256 + t] = f2bf(s);
  } else {
    const int bq = blockIdx.x - 2048;
    const size_t tid = (size_t)bq * 256 + t;
    const int tok0 = bq * 32;
    const int b = tok0 >> 13;
    ks[t] = kvr[(size_t)(b * 8 + (t >> 5)) * 2080 + 2048 + (t & 31)];
    __syncthreads();
    const int tok = (int)(tid >> 3), h = (int)(tid & 7);
    const short8* q = (const short8*)(QF + (size_t)tok * 256 + h * 32);
    short8 v[4];
    #pragma unroll
    for (int i = 0; i < 4; ++i) v[i] = q[i];
    float den = 1e-6f;
    #pragma unroll
    for (int i = 0; i < 4; ++i)
      #pragma unroll
      for (int j = 0; j < 8; ++j)
        den += bf2f((unsigned short)v[i][j]) * ks[h * 32 + i * 8 + j];
    const float inv = 1.f / den;
    short8* o = (short8*)(QN + (size_t)tok * 256 + h * 32);
    #pragma unroll
    for (int i = 0; i < 4; ++i) {
      short8 ov;
      #pragma unroll
      for (int j = 0; j < 8; ++j)
        ov[j] = (short)f2bf(bf2f((unsigned short)v[i][j]) * inv);
      o[i] = ov;
    }
  }
}

// ---------------- K4: out = qn @ M^T + bias (K=256) ----------------
__global__ __launch_bounds__(256) void gemm_out(
    const unsigned short* __restrict__ QN,   // 32768 x 256
    const unsigned short* __restrict__ MT,   // [4][512][256]
    const float* __restrict__ bias,
    float* __restrict__ OC) {
  __shared__ __attribute__((aligned(16))) unsigned short Bls[32768];  // 64 KB
  const int t = threadIdx.x;
  const int lane = t & 63, w = t >> 6;
  const int wr = w >> 1, wc = w & 1;
  const int col = lane & 15, kg = lane >> 4;

  const int nx = gridDim.x;
  int wg = blockIdx.y * nx + blockIdx.x;
  const int cpx = (nx * (int)gridDim.y) >> 3;
  wg = (wg & 7) * cpx + (wg >> 3);
  const int bx = wg % nx, by = wg / nx;
  const long m0 = (long)by * 128;
  const long n0 = (long)bx * 128;
  const long b = m0 >> 13;
  const unsigned short* MTb = MT + b * 512 * 256;

  #pragma unroll
  for (int i = 0; i < 16; ++i) {   // 16 x 4KB = 64KB staged
    const int u = i * 256 + t;
    const int slab = u >> 9, row = (u >> 2) & 127, ch = u & 3;
    gload16(MTb + ((size_t)(n0 + row)) * 256 + slab * 32 + ch * 8,
            Bls + ((size_t)i * 256 + w * 64) * 8);
  }
  __syncthreads();   // drains vmcnt(0): whole B-panel resident

  f32x4 acc[4][4] = {};
  #pragma unroll 2
  for (int kt = 0; kt < 8; ++kt) {
    short8 af[4], bfr[4];
    #pragma unroll
    for (int mi = 0; mi < 4; ++mi)
      af[mi] = *(const short8*)&QN[(m0 + wr * 64 + mi * 16 + col) * 256 +
                                   kt * 32 + kg * 8];
    #pragma unroll
    for (int ni = 0; ni < 4; ++ni)
      bfr[ni] = *(const short8*)&Bls[kt * 4096 +
                                     (wc * 64 + ni * 16 + col) * 32 + kg * 8];
    #pragma unroll
    for (int mi = 0; mi < 4; ++mi)
      #pragma unroll
      for (int ni = 0; ni < 4; ++ni)
        acc[mi][ni] = mfma16(af[mi], bfr[ni], acc[mi][ni]);
  }

  const int rowb = (int)m0 + wr * 64;
  const int colb = (int)n0 + wc * 64;
  #pragma unroll
  for (int ni = 0; ni < 4; ++ni) {
    const int c = colb + ni * 16 + col;
    const float bb = bias[c];
    #pragma unroll
    for (int mi = 0; mi < 4; ++mi) {
      #pragma unroll
      for (int r = 0; r < 4; ++r) {
        const int row = rowb + mi * 16 + kg * 4 + r;
        OC[(size_t)row * 512 + c] = acc[mi][ni][r] + bb;
      }
    }
  }
}

extern "C" void kernel_launch(void* const* d_in, const int* in_sizes, int n_in,
                              void* d_out, int out_size, void* d_ws, size_t ws_size,
                              hipStream_t stream) {
  const float* x    = (const float*)d_in[0];
  const float* Wqkv = (const float*)d_in[1];
  const float* rm   = (const float*)d_in[2];
  const float* Wout = (const float*)d_in[3];
  const float* bout = (const float*)d_in[4];
  float* out = (float*)d_out;

  char* ws = (char*)d_ws;
  unsigned short* QN    = (unsigned short*)(ws);              // 16,777,216 B
  unsigned short* MT    = (unsigned short*)(ws + 16777216);   //  1,048,576
  float* part           = (float*)(ws + 17825792);            // 17,039,360 (ends 34,865,152; overlays dead WcatT tail)
  unsigned short* WcatT = (unsigned short*)(ws + 33554432);   //  1,048,576 (dead before part written)
  unsigned short* QF    = (unsigned short*)(ws + 35127296);   // 16,777,216
  unsigned short* KFT   = (unsigned short*)(ws + 51904512);   // 16,777,216
  unsigned short* VT    = (unsigned short*)(ws + 68681728);   // 33,554,432
  float* kvr            = (float*)(ws + 110755840);           //    266,240

  if (ws_size < 111022080u) return;

  prep_w<<<dim3(1024), dim3(64), 0, stream>>>(Wqkv, rm, WcatT);
  gemm_qkv<<<dim3(8, 256), dim3(256), 0, stream>>>(x, WcatT, QF, KFT, VT);
  kv_partial<<<dim3(32, 64), dim3(64), 0, stream>>>(KFT, VT, part);
  kv_reduce<<<dim3(32), dim3(256), 0, stream>>>(part, kvr);
  mprep_qn<<<dim3(3072), dim3(256), 0, stream>>>(kvr, Wout, QF, MT, QN);
  gemm_out<<<dim3(4, 256), dim3(256), 0, stream>>>(QN, MT, bout, out);
}